// Round 8
// baseline (207.372 us; speedup 1.0000x reference)
//
#include <hip/hip_runtime.h>
#include <math.h>

#define NB   2
#define LVL  4
#define QQ   4096
#define LEN  16384   // LVL*QQ
#define CH   256
#define NH   8
#define DD   32
#define PP   4
#define HL   64
#define WL   64

typedef float    f32x4 __attribute__((ext_vector_type(4)));
typedef _Float16 h16x8 __attribute__((ext_vector_type(8)));
typedef _Float16 h16x2 __attribute__((ext_vector_type(2)));

__device__ __forceinline__ short h2s(_Float16 h) {
    union { _Float16 h; short s; } v; v.h = h; return v.s;
}
__device__ __forceinline__ _Float16 s2h(short s) {
    union { short s; _Float16 h; } v; v.s = s; return v.h;
}
__device__ __forceinline__ h16x2 u2h2(unsigned u) {
    union { unsigned u; h16x2 h; } v; v.u = u; return v.h;
}
__device__ __forceinline__ unsigned h22u(h16x2 h) {
    union { h16x2 h; unsigned u; } v; v.h = h; return v.u;
}

// Convert weights to fp16, transposed to [N][K], 16B-groups XOR-swizzled:
// WT[c][ (g&~7)|((g&7)^(c&7)) *8 + e ] = W[g*8+e][c]
__global__ __launch_bounds__(256) void prep_w(
    const float* __restrict__ W_val, const float* __restrict__ W_out,
    const float* __restrict__ W_off, const float* __restrict__ W_attn,
    short* __restrict__ WT_val, short* __restrict__ WT_out, short* __restrict__ WT_proj)
{
    const int id = blockIdx.x * 256 + threadIdx.x;   // 0 .. 229375
    if (id < 131072) {
        const int which = id >> 16;          // 0: W_val, 1: W_out
        const int u = id & 65535;
        const int c = u >> 8;                // WT row (output col), 0..255
        const int p = u & 255;               // stored position
        const int gp = p >> 3, e = p & 7;
        const int g = (gp & ~7) | ((gp & 7) ^ (c & 7));
        const int k = g * 8 + e;
        const float* W = which ? W_out : W_val;
        short* WT = which ? WT_out : WT_val;
        WT[(size_t)c * 256 + p] = h2s((_Float16)W[(size_t)k * 256 + c]);
    } else {
        const int u = id - 131072;           // 0 .. 98303
        const int i = u / (96 * 256);
        const int r = u % (96 * 256);
        const int c = r >> 8;                // 0..95
        const int p = r & 255;
        const int gp = p >> 3, e = p & 7;
        const int g = (gp & ~7) | ((gp & 7) ^ (c & 7));
        const int k = g * 8 + e;
        float w;
        if (c < 64) w = W_off[((size_t)i * 256 + k) * 64 + c];
        else        w = W_attn[((size_t)i * 256 + k) * 32 + (c - 64)];
        WT_proj[((size_t)i * 96 + c) * 256 + p] = h2s((_Float16)w);
    }
}

// MFMA GEMM (f16): C[M,N] = A[M,256] @ W[256,N] + bias.  BM=128, BK=64.
// MODE 0: A fp32, C fp16 (value proj)
// MODE 2: A fp32 = seq_query[ij], C fp16 proj layout, N=96 (blockIdx.y = ij)
// MODE 3: A = f16(Ain)+f16(Ain2) summed fp32, C fp32 (out proj w/ partials)
template<int MODE, int BN, int WN, int MR, int NR>
__global__ __launch_bounds__(256) void gemm_mfma(
    const void* __restrict__ Ain, const void* __restrict__ Ain2,
    const short* __restrict__ WT,
    const float* __restrict__ bias, const float* __restrict__ bias2,
    void* __restrict__ Cout)
{
    __shared__ short sA[128 * 64];     // 16 KB, XOR-swizzled
    __shared__ short sB[BN * 256];     // pre-swizzled rows [col][K]
    const int t    = threadIdx.x;
    const int lane = t & 63;
    const int wave = t >> 6;
    const int m0   = blockIdx.x * 128;

    int i = 0, j = 0, n0 = 0;
    const float* Af  = (const float*)Ain;
    const short* Ah  = (const short*)Ain;
    const short* Ah2 = (const short*)Ain2;
    const short* wt  = WT;
    if (MODE == 2) {
        const int ij = blockIdx.y;
        i = ij >> 2; j = ij & 3;
        Af += (size_t)ij * (NB * QQ) * CH;
        wt += (size_t)i * 96 * 256;
    } else {
        n0 = blockIdx.y * BN;
        wt += (size_t)n0 * 256;
    }

    // stage B once (whole K), linear copy of pre-swizzled rows
    for (int u = t; u < BN * 32; u += 256)
        *(int4*)(sB + (size_t)u * 8) = *(const int4*)(wt + (size_t)u * 8);

    f32x4 acc[MR][NR];
    #pragma unroll
    for (int m = 0; m < MR; ++m)
        #pragma unroll
        for (int n = 0; n < NR; ++n)
            acc[m][n] = (f32x4){0.f, 0.f, 0.f, 0.f};

    const int wr = wave / WN;
    const int wc = wave % WN;
    const int rbase = wr * MR * 16;
    const int cbase = wc * NR * 16;
    const int lr  = lane & 15;
    const int lkg = lane >> 4;

    for (int ko = 0; ko < 4; ++ko) {
        // stage A[128][64] f16 swizzled (fused convert for fp32 sources)
        #pragma unroll
        for (int v = 0; v < 4; ++v) {
            const int u = t + v * 256;
            const int row = u >> 3, g = u & 7;
            char* dst = (char*)sA + row * 128 + ((g ^ (row & 7)) << 4);
            const size_t aidx = (size_t)(m0 + row) * CH + ko * 64 + g * 8;
            if (MODE == 3) {
                const h16x8 a0 = *(const h16x8*)(Ah  + aidx);
                const h16x8 a1 = *(const h16x8*)(Ah2 + aidx);
                h16x8 w;
                #pragma unroll
                for (int e = 0; e < 8; ++e)
                    w[e] = (_Float16)((float)a0[e] + (float)a1[e]);
                *(h16x8*)dst = w;
            } else {
                const float* sp = Af + aidx;
                const float4 f0 = *(const float4*)sp;
                const float4 f1 = *(const float4*)(sp + 4);
                h16x8 w;
                w[0] = (_Float16)f0.x; w[1] = (_Float16)f0.y;
                w[2] = (_Float16)f0.z; w[3] = (_Float16)f0.w;
                w[4] = (_Float16)f1.x; w[5] = (_Float16)f1.y;
                w[6] = (_Float16)f1.z; w[7] = (_Float16)f1.w;
                *(h16x8*)dst = w;
            }
        }
        __syncthreads();
        #pragma unroll
        for (int s = 0; s < 2; ++s) {
            h16x8 afr[MR], bfr[NR];
            #pragma unroll
            for (int m = 0; m < MR; ++m) {
                const int row = rbase + m * 16 + lr;
                afr[m] = *(const h16x8*)((const char*)sA + row * 128 +
                                         (((s * 4 + lkg) ^ (row & 7)) << 4));
            }
            #pragma unroll
            for (int n = 0; n < NR; ++n) {
                const int col = cbase + n * 16 + lr;
                const int g  = ko * 8 + s * 4 + lkg;
                const int gp = (g & ~7) | ((g & 7) ^ (col & 7));
                bfr[n] = *(const h16x8*)((const char*)sB + (size_t)col * 512 + (gp << 4));
            }
            #pragma unroll
            for (int m = 0; m < MR; ++m)
                #pragma unroll
                for (int n = 0; n < NR; ++n)
                    acc[m][n] = __builtin_amdgcn_mfma_f32_16x16x32_f16(afr[m], bfr[n], acc[m][n], 0, 0, 0);
        }
        __syncthreads();
    }

    // epilogue: C/D mapping col=lane&15, row=(lane>>4)*4+reg
    #pragma unroll
    for (int m = 0; m < MR; ++m) {
        #pragma unroll
        for (int n = 0; n < NR; ++n) {
            #pragma unroll
            for (int r = 0; r < 4; ++r) {
                const int row = m0 + rbase + m * 16 + (lane >> 4) * 4 + r;
                const int col = cbase + n * 16 + lr;
                const float v = acc[m][n][r];
                if (MODE == 0) {
                    ((short*)Cout)[(size_t)row * CH + n0 + col] = h2s((_Float16)(v + bias[n0 + col]));
                } else if (MODE == 3) {
                    ((float*)Cout)[(size_t)row * CH + n0 + col] = v + bias[n0 + col];
                } else {
                    const int nb = row >> 12, q = row & 4095;
                    const float bc = (col < 64) ? bias[i * 64 + col] : bias2[i * 32 + (col - 64)];
                    ((short*)Cout)[((((size_t)nb * LVL + i) * QQ + q) * LVL + j) * 96 + col] = h2s((_Float16)(v + bc));
                }
            }
        }
    }
}

// Sampler: level-pair split + XCD pinning; 8 queries per block, 2 per wave.
// LDS slimmed to ~18 KB so 8 blocks/CU fit (32 waves = 100% occupancy);
// __launch_bounds__(256,8) caps VGPR at 64 to allow 8 waves/SIMD.
#define SQB 8
__global__ __launch_bounds__(256, 8) void sampler(
    const short* __restrict__ proj,              // (NB*LEN, 384) fp16
    const float* __restrict__ ref_pts,           // (NB, LEN, LVL, 2)
    const short* __restrict__ value,             // (NB, LEN, 256) fp16
    short* __restrict__ out_lp0,                 // partial, levels 0-1
    short* __restrict__ out_lp1)                 // partial, levels 2-3
{
    const int bid   = blockIdx.x;
    const int x     = bid & 7;
    const int combo = x & 3;
    const int rep   = x >> 2;
    const int n     = combo >> 1;
    const int lp    = combo & 1;
    const int l0    = lp * 2;
    const int chunk = (bid >> 3) * 2 + rep;      // 0..2047
    const int iq0   = chunk * SQB;
    const int qf0   = n * LEN + iq0;             // flat query base
    const int t     = threadIdx.x;

    // s_raw[q]: shorts 0..127 = offsets of our 2 levels (ll*64 + h*8+p*2+xy),
    //           shorts 128..255 = attn logits all 4 levels (128 + jj*32 + h*4+p)
    __shared__ short s_raw[SQB][256];            // 4 KB
    __shared__ float s_ref[SQB][2][2];           // 128 B
    __shared__ float s_aw [SQB][NH][8];          // 2 KB
    __shared__ int   s_off[SQB][64][4];          // 8 KB (byte offsets)
    __shared__ short s_wh [SQB][64][4];          // 4 KB (fp16 w*aw)

    // Phase A: stage needed proj dwords + ref points
    {
        for (int u = t; u < SQB * 128; u += 256) {
            const int q = u >> 7, w = u & 127;
            const unsigned* row = (const unsigned*)(proj + (size_t)(qf0 + q) * 384);
            unsigned d;
            if (w < 64) {                        // offsets, levels l0..l0+1
                const int ll = w >> 5, c = w & 31;
                d = row[(l0 + ll) * 48 + c];
            } else {                             // attn logits, all levels
                const int v = w - 64;
                const int jj = v >> 4, c = v & 15;
                d = row[jj * 48 + 32 + c];
            }
            ((unsigned*)s_raw)[q * 128 + w] = d;
        }
        if (t < SQB * 4) {
            const int q = t >> 2, ll = (t >> 1) & 1, xy = t & 1;
            s_ref[q][ll][xy] = ref_pts[((size_t)(qf0 + q) * LVL + l0 + ll) * 2 + xy];
        }
    }
    __syncthreads();

    // Phase B1: softmax, one thread per (q,h); keep aw of our 2 levels
    if (t < SQB * NH) {
        const int q = t >> 3, h = t & 7;
        float lg[16];
        #pragma unroll
        for (int jj = 0; jj < LVL; ++jj)
            #pragma unroll
            for (int p = 0; p < PP; ++p)
                lg[jj * 4 + p] = (float)s2h(s_raw[q][128 + jj * 32 + h * 4 + p]);
        float m = -1e30f;
        #pragma unroll
        for (int e = 0; e < 16; ++e) m = fmaxf(m, lg[e]);
        float s = 0.f;
        #pragma unroll
        for (int e = 0; e < 16; ++e) { lg[e] = __expf(lg[e] - m); s += lg[e]; }
        const float inv = 1.f / s;
        #pragma unroll
        for (int ll = 0; ll < 2; ++ll)
            #pragma unroll
            for (int p = 0; p < PP; ++p)
                s_aw[q][h][ll * 4 + p] = lg[(l0 + ll) * 4 + p] * inv;
    }
    __syncthreads();

    // Phase B2: corner tables, items (q,ll,p,h)
    for (int e = t; e < SQB * 64; e += 256) {
        const int q = e >> 6, r = e & 63;
        const int ll = r >> 5, p = (r >> 3) & 3, h = r & 7;
        const float ox = (float)s2h(s_raw[q][ll * 64 + h * 8 + p * 2 + 0]);
        const float oy = (float)s2h(s_raw[q][ll * 64 + h * 8 + p * 2 + 1]);
        const float aw = s_aw[q][h][ll * 4 + p];
        const float px = s_ref[q][ll][0] * (float)WL + ox - 0.5f;
        const float py = s_ref[q][ll][1] * (float)HL + oy - 0.5f;
        const float x0f = floorf(px), y0f = floorf(py);
        const float dx = px - x0f,   dy = py - y0f;
        const int   x0 = (int)x0f,   y0 = (int)y0f;
        #pragma unroll
        for (int c = 0; c < 4; ++c) {
            const int cx = c & 1, cy = c >> 1;
            const int gx = x0 + cx, gy = y0 + cy;
            const bool valid = ((unsigned)gx < (unsigned)WL) && ((unsigned)gy < (unsigned)HL);
            const int cgx = min(max(gx, 0), WL - 1);
            const int cgy = min(max(gy, 0), HL - 1);
            const float w = (cx ? dx : 1.f - dx) * (cy ? dy : 1.f - dy);
            const float wa = valid ? w * aw : 0.f;
            s_off[q][r][c] = ((l0 + ll) * QQ + cgy * WL + cgx) * (CH * 2);
            s_wh [q][r][c] = h2s((_Float16)wa);
        }
    }
    __syncthreads();

    // Main: wave = 2 queries; lane = (qsub, h, d8); 8 fp16 channels/thread.
    const int lane = t & 63;
    const int wv   = t >> 6;
    const int q    = wv * 2 + (lane >> 5);
    const int h    = (lane >> 2) & 7;
    const int d8   = lane & 3;
    const unsigned chan = (unsigned)(h * 64 + d8 * 16);  // byte offset of 8 ch
    const char* vb8 = (const char*)(value + (size_t)n * LEN * CH);

    h16x2 acc0 = (h16x2)0, acc1 = (h16x2)0, acc2 = (h16x2)0, acc3 = (h16x2)0;
    #pragma unroll
    for (int ll = 0; ll < 2; ++ll) {
        uint4 g[16];
        // issue 16 independent gathers
        #pragma unroll
        for (int p = 0; p < PP; ++p) {
            const int r = ll * 32 + p * 8 + h;
            const int4 offs = *(const int4*)&s_off[q][r][0];
            g[p * 4 + 0] = *(const uint4*)(vb8 + ((unsigned)offs.x + chan));
            g[p * 4 + 1] = *(const uint4*)(vb8 + ((unsigned)offs.y + chan));
            g[p * 4 + 2] = *(const uint4*)(vb8 + ((unsigned)offs.z + chan));
            g[p * 4 + 3] = *(const uint4*)(vb8 + ((unsigned)offs.w + chan));
        }
        // consume
        #pragma unroll
        for (int p = 0; p < PP; ++p) {
            const int r = ll * 32 + p * 8 + h;
            const ushort4 ws = *(const ushort4*)&s_wh[q][r][0];
            #pragma unroll
            for (int c = 0; c < 4; ++c) {
                const unsigned short wu = (c == 0) ? ws.x : (c == 1) ? ws.y : (c == 2) ? ws.z : ws.w;
                h16x2 w; w[0] = s2h((short)wu); w[1] = w[0];
                const uint4 gv = g[p * 4 + c];
                acc0 += w * u2h2(gv.x); acc1 += w * u2h2(gv.y);
                acc2 += w * u2h2(gv.z); acc3 += w * u2h2(gv.w);
            }
        }
    }

    short* outp = lp ? out_lp1 : out_lp0;
    uint4 st;
    st.x = h22u(acc0); st.y = h22u(acc1); st.z = h22u(acc2); st.w = h22u(acc3);
    *(uint4*)(outp + (size_t)(qf0 + q) * CH + h * DD + d8 * 8) = st;
}

extern "C" void kernel_launch(void* const* d_in, const int* in_sizes, int n_in,
                              void* d_out, int out_size, void* d_ws, size_t ws_size,
                              hipStream_t stream) {
    const float* seq_query = (const float*)d_in[0];
    const float* ref_pts   = (const float*)d_in[1];
    const float* input_fl  = (const float*)d_in[2];
    const float* W_off     = (const float*)d_in[3];
    const float* b_off     = (const float*)d_in[4];
    const float* W_attn    = (const float*)d_in[5];
    const float* b_attn    = (const float*)d_in[6];
    const float* W_val     = (const float*)d_in[7];
    const float* b_val     = (const float*)d_in[8];
    const float* W_out     = (const float*)d_in[9];
    const float* b_out     = (const float*)d_in[10];

    float* out = (float*)d_out;

    short* value   = (short*)d_ws;                                   // 16.8 MB
    short* out_lp0 = value   + (size_t)NB * LEN * CH;                // 16.8 MB
    short* out_lp1 = out_lp0 + (size_t)NB * LEN * CH;                // 16.8 MB
    short* WT_val  = out_lp1 + (size_t)NB * LEN * CH;                // 128 KB
    short* WT_out  = WT_val + 65536;                                 // 128 KB
    short* WT_proj = WT_out + 65536;                                 // 192 KB
    short* proj    = WT_proj + 4 * 96 * 256;                         // 25.2 MB

    // 0) weight prep: fp16, transposed, pre-swizzled
    prep_w<<<896, 256, 0, stream>>>(W_val, W_out, W_off, W_attn, WT_val, WT_out, WT_proj);

    // 1) value projection (fp32 in -> fp16 out)
    gemm_mfma<0, 64, 2, 4, 2><<<dim3(256, 4), 256, 0, stream>>>(
        input_fl, nullptr, WT_val, b_val, nullptr, value);

    // 2) offset/attn projection (16 GEMMs, fp32 in -> fp16 proj)
    gemm_mfma<2, 96, 1, 2, 6><<<dim3(64, 16), 256, 0, stream>>>(
        seq_query, nullptr, WT_proj, b_off, b_attn, proj);

    // 3) softmax + bilinear sampling, level-pair split (fp16 partials)
    sampler<<<(NB * LEN) / SQB * 2, 256, 0, stream>>>(
        proj, ref_pts, value, out_lp0, out_lp1);

    // 4) output projection (sum of partials, fp16 in -> fp32 d_out)
    gemm_mfma<3, 64, 2, 4, 2><<<dim3(256, 4), 256, 0, stream>>>(
        out_lp0, out_lp1, WT_out, b_out, nullptr, out);
}

// Round 9
// 164.925 us; speedup vs baseline: 1.2574x; 1.2574x over previous
//
#include <hip/hip_runtime.h>
#include <math.h>

#define NB   2
#define LVL  4
#define QQ   4096
#define LEN  16384   // LVL*QQ
#define CH   256
#define NH   8
#define DD   32
#define PP   4
#define HL   64
#define WL   64
#define PARTN ((size_t)NB * LEN * CH)   // elements per partial buffer

typedef float    f32x4 __attribute__((ext_vector_type(4)));
typedef _Float16 h16x8 __attribute__((ext_vector_type(8)));
typedef _Float16 h16x2 __attribute__((ext_vector_type(2)));

__device__ __forceinline__ short h2s(_Float16 h) {
    union { _Float16 h; short s; } v; v.h = h; return v.s;
}
__device__ __forceinline__ _Float16 s2h(short s) {
    union { short s; _Float16 h; } v; v.s = s; return v.h;
}
__device__ __forceinline__ h16x2 u2h2(unsigned u) {
    union { unsigned u; h16x2 h; } v; v.u = u; return v.h;
}
__device__ __forceinline__ unsigned h22u(h16x2 h) {
    union { h16x2 h; unsigned u; } v; v.h = h; return v.u;
}

// Convert weights to fp16, transposed to [N][K], 16B-groups XOR-swizzled:
// WT[c][ (g&~7)|((g&7)^(c&7)) *8 + e ] = W[g*8+e][c]
__global__ __launch_bounds__(256) void prep_w(
    const float* __restrict__ W_val, const float* __restrict__ W_out,
    const float* __restrict__ W_off, const float* __restrict__ W_attn,
    short* __restrict__ WT_val, short* __restrict__ WT_out, short* __restrict__ WT_proj)
{
    const int id = blockIdx.x * 256 + threadIdx.x;   // 0 .. 229375
    if (id < 131072) {
        const int which = id >> 16;          // 0: W_val, 1: W_out
        const int u = id & 65535;
        const int c = u >> 8;                // WT row (output col), 0..255
        const int p = u & 255;               // stored position
        const int gp = p >> 3, e = p & 7;
        const int g = (gp & ~7) | ((gp & 7) ^ (c & 7));
        const int k = g * 8 + e;
        const float* W = which ? W_out : W_val;
        short* WT = which ? WT_out : WT_val;
        WT[(size_t)c * 256 + p] = h2s((_Float16)W[(size_t)k * 256 + c]);
    } else {
        const int u = id - 131072;           // 0 .. 98303
        const int i = u / (96 * 256);
        const int r = u % (96 * 256);
        const int c = r >> 8;                // 0..95
        const int p = r & 255;
        const int gp = p >> 3, e = p & 7;
        const int g = (gp & ~7) | ((gp & 7) ^ (c & 7));
        const int k = g * 8 + e;
        float w;
        if (c < 64) w = W_off[((size_t)i * 256 + k) * 64 + c];
        else        w = W_attn[((size_t)i * 256 + k) * 32 + (c - 64)];
        WT_proj[((size_t)i * 96 + c) * 256 + p] = h2s((_Float16)w);
    }
}

// MFMA GEMM (f16): C[M,N] = A[M,256] @ W[256,N] + bias.  BM=128, BK=64.
// MODE 0: A fp32, C fp16 (value proj)
// MODE 2: A fp32 = seq_query[ij], C fp16 proj layout, N=96 (blockIdx.y = ij)
// MODE 4: A = sum of 4 fp16 partials (Ain + k*PARTN), C fp32 (out proj)
template<int MODE, int BN, int WN, int MR, int NR>
__global__ __launch_bounds__(256) void gemm_mfma(
    const void* __restrict__ Ain, const short* __restrict__ WT,
    const float* __restrict__ bias, const float* __restrict__ bias2,
    void* __restrict__ Cout)
{
    __shared__ short sA[128 * 64];     // 16 KB, XOR-swizzled
    __shared__ short sB[BN * 256];     // pre-swizzled rows [col][K]
    const int t    = threadIdx.x;
    const int lane = t & 63;
    const int wave = t >> 6;
    const int m0   = blockIdx.x * 128;

    int i = 0, j = 0, n0 = 0;
    const float* Af = (const float*)Ain;
    const short* Ah = (const short*)Ain;
    const short* wt = WT;
    if (MODE == 2) {
        const int ij = blockIdx.y;
        i = ij >> 2; j = ij & 3;
        Af += (size_t)ij * (NB * QQ) * CH;
        wt += (size_t)i * 96 * 256;
    } else {
        n0 = blockIdx.y * BN;
        wt += (size_t)n0 * 256;
    }

    // stage B once (whole K), linear copy of pre-swizzled rows
    for (int u = t; u < BN * 32; u += 256)
        *(int4*)(sB + (size_t)u * 8) = *(const int4*)(wt + (size_t)u * 8);

    f32x4 acc[MR][NR];
    #pragma unroll
    for (int m = 0; m < MR; ++m)
        #pragma unroll
        for (int n = 0; n < NR; ++n)
            acc[m][n] = (f32x4){0.f, 0.f, 0.f, 0.f};

    const int wr = wave / WN;
    const int wc = wave % WN;
    const int rbase = wr * MR * 16;
    const int cbase = wc * NR * 16;
    const int lr  = lane & 15;
    const int lkg = lane >> 4;

    for (int ko = 0; ko < 4; ++ko) {
        // stage A[128][64] f16 swizzled (fused convert / partial-sum)
        #pragma unroll
        for (int v = 0; v < 4; ++v) {
            const int u = t + v * 256;
            const int row = u >> 3, g = u & 7;
            char* dst = (char*)sA + row * 128 + ((g ^ (row & 7)) << 4);
            const size_t aidx = (size_t)(m0 + row) * CH + ko * 64 + g * 8;
            if (MODE == 4) {
                const h16x8 a0 = *(const h16x8*)(Ah + aidx);
                const h16x8 a1 = *(const h16x8*)(Ah + aidx + PARTN);
                const h16x8 a2 = *(const h16x8*)(Ah + aidx + 2 * PARTN);
                const h16x8 a3 = *(const h16x8*)(Ah + aidx + 3 * PARTN);
                h16x8 w;
                #pragma unroll
                for (int e = 0; e < 8; ++e)
                    w[e] = (_Float16)(((float)a0[e] + (float)a1[e]) +
                                      ((float)a2[e] + (float)a3[e]));
                *(h16x8*)dst = w;
            } else {
                const float* sp = Af + aidx;
                const float4 f0 = *(const float4*)sp;
                const float4 f1 = *(const float4*)(sp + 4);
                h16x8 w;
                w[0] = (_Float16)f0.x; w[1] = (_Float16)f0.y;
                w[2] = (_Float16)f0.z; w[3] = (_Float16)f0.w;
                w[4] = (_Float16)f1.x; w[5] = (_Float16)f1.y;
                w[6] = (_Float16)f1.z; w[7] = (_Float16)f1.w;
                *(h16x8*)dst = w;
            }
        }
        __syncthreads();
        #pragma unroll
        for (int s = 0; s < 2; ++s) {
            h16x8 afr[MR], bfr[NR];
            #pragma unroll
            for (int m = 0; m < MR; ++m) {
                const int row = rbase + m * 16 + lr;
                afr[m] = *(const h16x8*)((const char*)sA + row * 128 +
                                         (((s * 4 + lkg) ^ (row & 7)) << 4));
            }
            #pragma unroll
            for (int n = 0; n < NR; ++n) {
                const int col = cbase + n * 16 + lr;
                const int g  = ko * 8 + s * 4 + lkg;
                const int gp = (g & ~7) | ((g & 7) ^ (col & 7));
                bfr[n] = *(const h16x8*)((const char*)sB + (size_t)col * 512 + (gp << 4));
            }
            #pragma unroll
            for (int m = 0; m < MR; ++m)
                #pragma unroll
                for (int n = 0; n < NR; ++n)
                    acc[m][n] = __builtin_amdgcn_mfma_f32_16x16x32_f16(afr[m], bfr[n], acc[m][n], 0, 0, 0);
        }
        __syncthreads();
    }

    // epilogue: C/D mapping col=lane&15, row=(lane>>4)*4+reg
    #pragma unroll
    for (int m = 0; m < MR; ++m) {
        #pragma unroll
        for (int n = 0; n < NR; ++n) {
            #pragma unroll
            for (int r = 0; r < 4; ++r) {
                const int row = m0 + rbase + m * 16 + (lane >> 4) * 4 + r;
                const int col = cbase + n * 16 + lr;
                const float v = acc[m][n][r];
                if (MODE == 0) {
                    ((short*)Cout)[(size_t)row * CH + n0 + col] = h2s((_Float16)(v + bias[n0 + col]));
                } else if (MODE == 4) {
                    ((float*)Cout)[(size_t)row * CH + n0 + col] = v + bias[n0 + col];
                } else {
                    const int nb = row >> 12, q = row & 4095;
                    const float bc = (col < 64) ? bias[i * 64 + col] : bias2[i * 32 + (col - 64)];
                    ((short*)Cout)[((((size_t)nb * LVL + i) * QQ + q) * LVL + j) * 96 + col] = h2s((_Float16)(v + bc));
                }
            }
        }
    }
}

// Sampler: ONE (n, level) combo per block, combo = bid&7 -> 1:1 with the 8
// XCDs (round-robin dispatch). Each XCD gathers from a 2.1 MB value slice
// that fits its 4 MB L2. 8 queries/block, 2 per wave; writes fp16 partial
// out_part[l]. LDS ~10 KB -> 8 blocks/CU; no VGPR cap (avoid scratch spill).
#define SQB 8
__global__ __launch_bounds__(256) void sampler(
    const short* __restrict__ proj,              // (NB*LEN, 384) fp16
    const float* __restrict__ ref_pts,           // (NB, LEN, LVL, 2)
    const short* __restrict__ value,             // (NB, LEN, 256) fp16
    short* __restrict__ out_part)                // 4 partials of (NB*LEN, 256)
{
    const int bid   = blockIdx.x;
    const int combo = bid & 7;                   // XCD id under %8 round-robin
    const int n     = combo >> 2;                // batch
    const int l     = combo & 3;                 // level
    const int chunk = bid >> 3;                  // 0..2047
    const int iq0   = chunk * SQB;
    const int qf0   = n * LEN + iq0;             // flat query base
    const int t     = threadIdx.x;

    // s_raw[q] (dwords 0..95): [0..31] = my level's offsets (64 shorts),
    //                          [32..95] = attn logits all 4 levels (jj*16+c)
    __shared__ short s_raw[SQB][192];            // 3 KB
    __shared__ float s_ref[SQB][2];              // 64 B
    __shared__ float s_aw [SQB][NH][PP];         // 1 KB
    __shared__ int   s_off[SQB][32][4];          // 4 KB (byte offsets)
    __shared__ short s_wh [SQB][32][4];          // 2 KB (fp16 w*aw)

    // Phase A: stage proj at 64B-line granularity (fully-used lines only)
    for (int u = t; u < SQB * 96; u += 256) {
        const int q = u / 96, w = u % 96;
        const unsigned* row = (const unsigned*)(proj + (size_t)(qf0 + q) * 384);
        unsigned d;
        if (w < 32) d = row[l * 48 + w];                               // offsets
        else        d = row[((w - 32) >> 4) * 48 + 32 + ((w - 32) & 15)]; // attn
        ((unsigned*)&s_raw[q][0])[w] = d;
    }
    if (t < SQB * 2) {
        const int q = t >> 1, xy = t & 1;
        s_ref[q][xy] = ref_pts[((size_t)(qf0 + q) * LVL + l) * 2 + xy];
    }
    __syncthreads();

    // Phase B1: softmax, one thread per (q,h); keep aw of my level
    if (t < SQB * NH) {
        const int q = t >> 3, h = t & 7;
        float lg[16];
        #pragma unroll
        for (int jj = 0; jj < LVL; ++jj)
            #pragma unroll
            for (int p = 0; p < PP; ++p)
                lg[jj * 4 + p] = (float)s2h(s_raw[q][64 + jj * 32 + h * 4 + p]);
        float m = -1e30f;
        #pragma unroll
        for (int e = 0; e < 16; ++e) m = fmaxf(m, lg[e]);
        float s = 0.f;
        #pragma unroll
        for (int e = 0; e < 16; ++e) { lg[e] = __expf(lg[e] - m); s += lg[e]; }
        const float inv = 1.f / s;
        #pragma unroll
        for (int p = 0; p < PP; ++p)
            s_aw[q][h][p] = lg[l * 4 + p] * inv;
    }
    __syncthreads();

    // Phase B2: corner tables, one thread per (q,p,h) = 256 items
    {
        const int q = t >> 5, r = t & 31;
        const int p = (r >> 3) & 3, h = r & 7;
        const float ox = (float)s2h(s_raw[q][h * 8 + p * 2 + 0]);
        const float oy = (float)s2h(s_raw[q][h * 8 + p * 2 + 1]);
        const float aw = s_aw[q][h][p];
        const float px = s_ref[q][0] * (float)WL + ox - 0.5f;
        const float py = s_ref[q][1] * (float)HL + oy - 0.5f;
        const float x0f = floorf(px), y0f = floorf(py);
        const float dx = px - x0f,   dy = py - y0f;
        const int   x0 = (int)x0f,   y0 = (int)y0f;
        #pragma unroll
        for (int c = 0; c < 4; ++c) {
            const int cx = c & 1, cy = c >> 1;
            const int gx = x0 + cx, gy = y0 + cy;
            const bool valid = ((unsigned)gx < (unsigned)WL) && ((unsigned)gy < (unsigned)HL);
            const int cgx = min(max(gx, 0), WL - 1);
            const int cgy = min(max(gy, 0), HL - 1);
            const float w = (cx ? dx : 1.f - dx) * (cy ? dy : 1.f - dy);
            const float wa = valid ? w * aw : 0.f;
            s_off[q][r][c] = (l * QQ + cgy * WL + cgx) * (CH * 2);
            s_wh [q][r][c] = h2s((_Float16)wa);
        }
    }
    __syncthreads();

    // Main: wave = 2 queries; lane = (qsub, h, d8); 8 fp16 channels/thread.
    const int lane = t & 63;
    const int wv   = t >> 6;
    const int q    = wv * 2 + (lane >> 5);
    const int h    = (lane >> 2) & 7;
    const int d8   = lane & 3;
    const unsigned chan = (unsigned)(h * 64 + d8 * 16);  // byte offset of 8 ch
    const char* vb8 = (const char*)(value + (size_t)n * LEN * CH);

    h16x2 acc0 = (h16x2)0, acc1 = (h16x2)0, acc2 = (h16x2)0, acc3 = (h16x2)0;
    {
        uint4 g[16];
        // issue 16 independent gathers
        #pragma unroll
        for (int p = 0; p < PP; ++p) {
            const int r = p * 8 + h;
            const int4 offs = *(const int4*)&s_off[q][r][0];
            g[p * 4 + 0] = *(const uint4*)(vb8 + ((unsigned)offs.x + chan));
            g[p * 4 + 1] = *(const uint4*)(vb8 + ((unsigned)offs.y + chan));
            g[p * 4 + 2] = *(const uint4*)(vb8 + ((unsigned)offs.z + chan));
            g[p * 4 + 3] = *(const uint4*)(vb8 + ((unsigned)offs.w + chan));
        }
        // consume
        #pragma unroll
        for (int p = 0; p < PP; ++p) {
            const int r = p * 8 + h;
            const ushort4 ws = *(const ushort4*)&s_wh[q][r][0];
            #pragma unroll
            for (int c = 0; c < 4; ++c) {
                const unsigned short wu = (c == 0) ? ws.x : (c == 1) ? ws.y : (c == 2) ? ws.z : ws.w;
                h16x2 w; w[0] = s2h((short)wu); w[1] = w[0];
                const uint4 gv = g[p * 4 + c];
                acc0 += w * u2h2(gv.x); acc1 += w * u2h2(gv.y);
                acc2 += w * u2h2(gv.z); acc3 += w * u2h2(gv.w);
            }
        }
    }

    short* outp = out_part + (size_t)l * PARTN;
    uint4 st;
    st.x = h22u(acc0); st.y = h22u(acc1); st.z = h22u(acc2); st.w = h22u(acc3);
    *(uint4*)(outp + (size_t)(qf0 + q) * CH + h * DD + d8 * 8) = st;
}

extern "C" void kernel_launch(void* const* d_in, const int* in_sizes, int n_in,
                              void* d_out, int out_size, void* d_ws, size_t ws_size,
                              hipStream_t stream) {
    const float* seq_query = (const float*)d_in[0];
    const float* ref_pts   = (const float*)d_in[1];
    const float* input_fl  = (const float*)d_in[2];
    const float* W_off     = (const float*)d_in[3];
    const float* b_off     = (const float*)d_in[4];
    const float* W_attn    = (const float*)d_in[5];
    const float* b_attn    = (const float*)d_in[6];
    const float* W_val     = (const float*)d_in[7];
    const float* b_val     = (const float*)d_in[8];
    const float* W_out     = (const float*)d_in[9];
    const float* b_out     = (const float*)d_in[10];

    float* out = (float*)d_out;

    short* value    = (short*)d_ws;                                  // 16.8 MB
    short* out_part = value + PARTN;                                 // 4 x 16.8 MB
    short* WT_val   = out_part + 4 * PARTN;                          // 128 KB
    short* WT_out   = WT_val + 65536;                                // 128 KB
    short* WT_proj  = WT_out + 65536;                                // 192 KB
    short* proj     = WT_proj + 4 * 96 * 256;                        // 25.2 MB

    // 0) weight prep: fp16, transposed, pre-swizzled
    prep_w<<<896, 256, 0, stream>>>(W_val, W_out, W_off, W_attn, WT_val, WT_out, WT_proj);

    // 1) value projection (fp32 in -> fp16 out)
    gemm_mfma<0, 64, 2, 4, 2><<<dim3(256, 4), 256, 0, stream>>>(
        input_fl, WT_val, b_val, nullptr, value);

    // 2) offset/attn projection (16 GEMMs, fp32 in -> fp16 proj)
    gemm_mfma<2, 96, 1, 2, 6><<<dim3(64, 16), 256, 0, stream>>>(
        seq_query, WT_proj, b_off, b_attn, proj);

    // 3) softmax + bilinear sampling, per-(n,level) XCD pinning (fp16 partials)
    sampler<<<(NB * LEN) / SQB * 4, 256, 0, stream>>>(
        proj, ref_pts, value, out_part);

    // 4) output projection (sum of 4 partials, fp16 in -> fp32 d_out)
    gemm_mfma<4, 64, 2, 4, 2><<<dim3(256, 4), 256, 0, stream>>>(
        out_part, WT_out, b_out, nullptr, out);
}